// Round 1
// baseline (399.274 us; speedup 1.0000x reference)
//
#include <hip/hip_runtime.h>

// Problem constants (fixed by reference: NUM_SAMPLES=8192, EMBED=64, TAU=0.2)
#define EMBED   64
#define NS      8192
#define CHUNK   512                 // j-elements per block in main kernel
#define NCHUNK  (NS / CHUNK)        // 16
#define INV_TAU 5.0f

// ---------------------------------------------------------------------------
// K1: gather selected rows of users/items into compact E[2][NS][EMBED] in ws.
// One thread copies one float4. Writes fully coalesced.
// ---------------------------------------------------------------------------
__global__ __launch_bounds__(256) void gather_kernel(
    const float* __restrict__ users, const float* __restrict__ items,
    const int* __restrict__ uidx, const int* __restrict__ iidx,
    float4* __restrict__ E) {
  int t = blockIdx.x * 256 + threadIdx.x;   // 0 .. 2*NS*16-1
  int mat = t >> 17;                        // NS*16 = 131072 = 2^17
  int rem = t & 131071;
  int row = rem >> 4;                       // 0..NS-1
  int q   = rem & 15;                       // float4 index within row
  int src = (mat == 0) ? uidx[row] : iidx[row];
  const float4* base = (const float4*)((mat == 0) ? users : items);
  E[t] = base[src * 16 + q];
}

// ---------------------------------------------------------------------------
// K2: per-row partial exp-sums with fixed shift diag_i.
//   rowpart[chunk][mat*NS+row] = sum_{j in chunk} exp((E_i.E_j - E_i.E_i)*INV_TAU)
// Thread = one row i. E_i lives in 64 VGPRs. E_j address is block-uniform
// (scalar loads / L1-broadcast). No LDS, no atomics.
// Grid: 2 mats * NCHUNK * 32 rowblocks = 1024 blocks of 256.
// ---------------------------------------------------------------------------
__global__ __launch_bounds__(256) void ssm_main_kernel(
    const float* __restrict__ E, float* __restrict__ rowpart) {
  int b = blockIdx.x;
  int rowblk = b & 31;            // 32 row-blocks of 256 rows
  int chunk  = (b >> 5) & (NCHUNK - 1);
  int mat    = b >> 9;            // b / (32*NCHUNK)
  int row = (rowblk << 8) + threadIdx.x;

  const float* Em = E + mat * (NS * EMBED);

  // Load my row into registers.
  float ei[EMBED];
  const float4* eir = (const float4*)(Em + row * EMBED);
  #pragma unroll
  for (int k = 0; k < 16; ++k) {
    float4 v = eir[k];
    ei[4*k+0] = v.x; ei[4*k+1] = v.y; ei[4*k+2] = v.z; ei[4*k+3] = v.w;
  }
  float diag = 0.f;
  #pragma unroll
  for (int k = 0; k < EMBED; ++k) diag = fmaf(ei[k], ei[k], diag);

  float acc = 0.f;
  const float* ej = Em + (chunk * CHUNK) * EMBED;   // block-uniform pointer
  for (int j = 0; j < CHUNK; ++j) {
    // 4 independent FMA chains to cut dependency latency 256->64 cyc.
    float r0 = 0.f, r1 = 0.f, r2 = 0.f, r3 = 0.f;
    #pragma unroll
    for (int k = 0; k < EMBED; k += 4) {
      r0 = fmaf(ei[k+0], ej[k+0], r0);
      r1 = fmaf(ei[k+1], ej[k+1], r1);
      r2 = fmaf(ei[k+2], ej[k+2], r2);
      r3 = fmaf(ei[k+3], ej[k+3], r3);
    }
    float r = (r0 + r1) + (r2 + r3);
    acc += __expf((r - diag) * INV_TAU);
    ej += EMBED;
  }
  rowpart[chunk * (2 * NS) + mat * NS + row] = acc;
}

// ---------------------------------------------------------------------------
// K3: finalize. Sum chunk partials per row, log, mean per matrix, write out.
// Single block of 1024 threads (reads 1 MB from L2, ~µs).
// out[0] = loss_u + loss_i, out[1] = loss_u, out[2] = loss_i
// ---------------------------------------------------------------------------
__global__ __launch_bounds__(1024) void finalize_kernel(
    const float* __restrict__ rowpart, float* __restrict__ out) {
  float lu = 0.f, li = 0.f;
  for (int r = threadIdx.x; r < 2 * NS; r += 1024) {
    float s = 0.f;
    #pragma unroll
    for (int c = 0; c < NCHUNK; ++c) s += rowpart[c * (2 * NS) + r];
    float l = logf(s);
    if (r < NS) lu += l; else li += l;
  }
  // wave reduce (64 lanes)
  #pragma unroll
  for (int off = 32; off; off >>= 1) {
    lu += __shfl_down(lu, off);
    li += __shfl_down(li, off);
  }
  __shared__ float red[2][16];
  int wave = threadIdx.x >> 6;
  if ((threadIdx.x & 63) == 0) { red[0][wave] = lu; red[1][wave] = li; }
  __syncthreads();
  if (threadIdx.x == 0) {
    float su = 0.f, si = 0.f;
    #pragma unroll
    for (int w = 0; w < 16; ++w) { su += red[0][w]; si += red[1][w]; }
    su *= (1.0f / NS);
    si *= (1.0f / NS);
    out[0] = su + si;
    out[1] = su;
    out[2] = si;
  }
}

// ---------------------------------------------------------------------------
// ws layout: E = 2*NS*EMBED floats (4 MB), rowpart = NCHUNK*2*NS floats (1 MB)
// ---------------------------------------------------------------------------
extern "C" void kernel_launch(void* const* d_in, const int* in_sizes, int n_in,
                              void* d_out, int out_size, void* d_ws, size_t ws_size,
                              hipStream_t stream) {
  const float* users = (const float*)d_in[0];
  const float* items = (const float*)d_in[1];
  const int*   uidx  = (const int*)d_in[2];
  const int*   iidx  = (const int*)d_in[3];
  float* out = (float*)d_out;

  float* E       = (float*)d_ws;                 // 2*NS*EMBED = 1,048,576 floats
  float* rowpart = E + 2 * NS * EMBED;           // NCHUNK*2*NS = 262,144 floats

  gather_kernel<<<(2 * NS * 16) / 256, 256, 0, stream>>>(users, items, uidx, iidx, (float4*)E);
  ssm_main_kernel<<<2 * NCHUNK * 32, 256, 0, stream>>>(E, rowpart);
  finalize_kernel<<<1, 1024, 0, stream>>>(rowpart, out);
}

// Round 2
// 144.665 us; speedup vs baseline: 2.7600x; 2.7600x over previous
//
#include <hip/hip_runtime.h>

// Problem constants (reference: NUM_SAMPLES=8192, EMBED=64, TAU=0.2)
#define EMBED    64
#define NS       8192
#define INV_TAU  5.0f
#define NTILE    256           // NS/32 row-tiles per matrix
#define JCHUNKS  8
#define JT_PER_CHUNK 32        // (NS/32)/JCHUNKS j-tiles per chunk

typedef _Float16 half8  __attribute__((ext_vector_type(8)));
typedef float    f32x16 __attribute__((ext_vector_type(16)));

// async global->LDS, 16B per lane. ldsptr is wave-uniform base (HW adds lane*16).
#define GLDS16(g, l) __builtin_amdgcn_global_load_lds( \
    (const __attribute__((address_space(1))) void*)(g), \
    (__attribute__((address_space(3))) void*)(l), 16, 0, 0)

// ---------------------------------------------------------------------------
// Prep: gather rows, split f32 -> (h,l) fp16 pair, compute diag = ||e||^2,
// and write fragment-major layout:
//   Efrag[mat][tile(256)][frag(8)][lane(64)][8 f16]   (frag = hl*4 + ktile)
// MFMA 32x32x16 fragment element for lane l, j in 0..7:
//   row/col = l&31, k = kt*16 + (l>>5)*8 + j
// Block = one (mat, tile) = 32 rows.
// ---------------------------------------------------------------------------
__global__ __launch_bounds__(256) void prep_kernel(
    const float* __restrict__ users, const float* __restrict__ items,
    const int* __restrict__ uidx, const int* __restrict__ iidx,
    _Float16* __restrict__ Efrag, float* __restrict__ diag) {
  int b = blockIdx.x;
  int mat = b >> 8, tile = b & 255;
  int t = threadIdx.x;
  int row8 = t >> 3, c8 = t & 7;          // 8 threads per row, 32B each
  int row = tile * 32 + row8;
  int src = mat ? iidx[row] : uidx[row];
  const float4* base = (const float4*)((mat ? items : users) + (size_t)src * EMBED);
  float4 v0 = base[c8 * 2], v1 = base[c8 * 2 + 1];

  __shared__ __align__(16) _Float16 Lh[32][64];
  __shared__ __align__(16) _Float16 Ll[32][64];

  float vs[8] = {v0.x, v0.y, v0.z, v0.w, v1.x, v1.y, v1.z, v1.w};
  float p = 0.f;
  #pragma unroll
  for (int j = 0; j < 8; ++j) {
    float v = vs[j];
    _Float16 h = (_Float16)v;
    _Float16 l = (_Float16)(v - (float)h);
    Lh[row8][c8 * 8 + j] = h;
    Ll[row8][c8 * 8 + j] = l;
    p = fmaf(v, v, p);
  }
  // reduce ||e||^2 over the 8 threads of this row (aligned 8-lane groups)
  p += __shfl_xor(p, 1);
  p += __shfl_xor(p, 2);
  p += __shfl_xor(p, 4);
  if (c8 == 0) diag[mat * NS + row] = p;
  __syncthreads();

  // fragment-major writeout: 8 frags x 64 lane-slots = 512 slots, 2 per thread
  #pragma unroll
  for (int s = t; s < 512; s += 256) {
    int f = s >> 6, lam = s & 63;
    int hl = f >> 2, kt = f & 3;
    int rr = lam & 31, k0 = kt * 16 + (lam >> 5) * 8;
    const _Float16* Lsrc = hl ? &Ll[0][0] : &Lh[0][0];
    half8 val = *(const half8*)(Lsrc + rr * 64 + k0);
    *(half8*)(Efrag + (((size_t)(mat * NTILE + tile) * 8 + f) * 64 + lam) * 8) = val;
  }
}

// ---------------------------------------------------------------------------
// Main: r = E E^T via 3 split-product MFMAs (hh + hl + lh), fixed-shift exp,
// per-row partial sums. Wave = 32-row strip; block = 4 waves = 128 rows;
// grid = 2 mats x 64 rowblocks x 8 j-chunks = 1024 blocks.
// B j-tiles (h+l = 8KB) double-buffered in LDS via global_load_lds(16B).
// ---------------------------------------------------------------------------
__global__ __launch_bounds__(256) void ssm_mfma_kernel(
    const _Float16* __restrict__ Efrag, const float* __restrict__ diag,
    float* __restrict__ rowpart) {
  int b = blockIdx.x;
  int jc  = b & (JCHUNKS - 1);
  int rb  = (b >> 3) & 63;
  int mat = b >> 9;
  int wave = threadIdx.x >> 6;
  int lane = threadIdx.x & 63;
  int hf   = lane >> 5;

  int rowtile = rb * 4 + wave;
  int rowbase = rowtile * 32;

  const _Float16* Em = Efrag + (size_t)mat * NTILE * 8 * 512;  // 8KB per tile

  // A fragments for my 32-row strip: a[0..3]=h ktiles, a[4..7]=l ktiles
  half8 a[8];
  #pragma unroll
  for (int f = 0; f < 8; ++f)
    a[f] = *(const half8*)(Em + (((size_t)rowtile * 8 + f) * 64 + lane) * 8);

  // diag values for my 16 accumulator slots (C row = (r&3)+8*(r>>2)+4*hf)
  float dv[16];
  #pragma unroll
  for (int r = 0; r < 16; ++r) {
    int rowl = (r & 3) + 8 * (r >> 2) + 4 * hf;
    dv[r] = diag[mat * NS + rowbase + rowl];
  }

  float rs[16];
  #pragma unroll
  for (int r = 0; r < 16; ++r) rs[r] = 0.f;

  __shared__ __align__(16) _Float16 Bbuf[2][8][64][8];  // 2 x 8KB

  int jt0 = jc * JT_PER_CHUNK;
  auto stage = [&](int buf, int jt) {
    const char* src = (const char*)(Em + (size_t)(jt0 + jt) * 8 * 512);
    char* dst = (char*)&Bbuf[buf][0][0][0];
    int o = wave * 2048;
    GLDS16(src + o + lane * 16, dst + o);
    GLDS16(src + o + 1024 + lane * 16, dst + o + 1024);
  };

  stage(0, 0);
  __syncthreads();   // drains vmcnt before first use

  for (int jt = 0; jt < JT_PER_CHUNK; ++jt) {
    int cur = jt & 1;
    if (jt + 1 < JT_PER_CHUNK) stage(cur ^ 1, jt + 1);

    half8 bh[4], bl[4];
    #pragma unroll
    for (int kt = 0; kt < 4; ++kt) {
      bh[kt] = *(const half8*)&Bbuf[cur][kt][lane][0];
      bl[kt] = *(const half8*)&Bbuf[cur][4 + kt][lane][0];
    }

    f32x16 acc = {0.f,0.f,0.f,0.f,0.f,0.f,0.f,0.f,
                  0.f,0.f,0.f,0.f,0.f,0.f,0.f,0.f};
    #pragma unroll
    for (int kt = 0; kt < 4; ++kt)
      acc = __builtin_amdgcn_mfma_f32_32x32x16_f16(a[kt], bh[kt], acc, 0, 0, 0);     // h*h
    #pragma unroll
    for (int kt = 0; kt < 4; ++kt)
      acc = __builtin_amdgcn_mfma_f32_32x32x16_f16(a[kt], bl[kt], acc, 0, 0, 0);     // h*l
    #pragma unroll
    for (int kt = 0; kt < 4; ++kt)
      acc = __builtin_amdgcn_mfma_f32_32x32x16_f16(a[4 + kt], bh[kt], acc, 0, 0, 0); // l*h

    #pragma unroll
    for (int r = 0; r < 16; ++r)
      rs[r] += __expf((acc[r] - dv[r]) * INV_TAU);

    __syncthreads();   // vmcnt(0)+lgkmcnt(0) drain: next buffer staged, reads done
  }

  // reduce each row partial across the 32 lanes of its half, write rowpart
  #pragma unroll
  for (int r = 0; r < 16; ++r) {
    float v = rs[r];
    v += __shfl_xor(v, 16);
    v += __shfl_xor(v, 8);
    v += __shfl_xor(v, 4);
    v += __shfl_xor(v, 2);
    v += __shfl_xor(v, 1);
    if ((lane & 31) == 0) {
      int rowl = (r & 3) + 8 * (r >> 2) + 4 * hf;
      rowpart[jc * (2 * NS) + mat * NS + rowbase + rowl] = v;
    }
  }
}

// ---------------------------------------------------------------------------
// Finalize: per-row chunk-sum, log, per-matrix mean.
// out[0] = loss_u + loss_i, out[1] = loss_u, out[2] = loss_i
// ---------------------------------------------------------------------------
__global__ __launch_bounds__(1024) void finalize_kernel(
    const float* __restrict__ rowpart, float* __restrict__ out) {
  float lu = 0.f, li = 0.f;
  for (int r = threadIdx.x; r < 2 * NS; r += 1024) {
    float s = 0.f;
    #pragma unroll
    for (int c = 0; c < JCHUNKS; ++c) s += rowpart[c * (2 * NS) + r];
    float l = logf(s);
    if (r < NS) lu += l; else li += l;
  }
  #pragma unroll
  for (int off = 32; off; off >>= 1) {
    lu += __shfl_down(lu, off);
    li += __shfl_down(li, off);
  }
  __shared__ float red[2][16];
  int wave = threadIdx.x >> 6;
  if ((threadIdx.x & 63) == 0) { red[0][wave] = lu; red[1][wave] = li; }
  __syncthreads();
  if (threadIdx.x == 0) {
    float su = 0.f, si = 0.f;
    #pragma unroll
    for (int w = 0; w < 16; ++w) { su += red[0][w]; si += red[1][w]; }
    su *= (1.0f / NS);
    si *= (1.0f / NS);
    out[0] = su + si;
    out[1] = su;
    out[2] = si;
  }
}

// ---------------------------------------------------------------------------
// ws layout: Efrag 4MB | diag 64KB | rowpart 512KB  (total ~4.6MB)
// ---------------------------------------------------------------------------
extern "C" void kernel_launch(void* const* d_in, const int* in_sizes, int n_in,
                              void* d_out, int out_size, void* d_ws, size_t ws_size,
                              hipStream_t stream) {
  const float* users = (const float*)d_in[0];
  const float* items = (const float*)d_in[1];
  const int*   uidx  = (const int*)d_in[2];
  const int*   iidx  = (const int*)d_in[3];
  float* out = (float*)d_out;

  _Float16* Efrag = (_Float16*)d_ws;                                   // 2*256*8*512 f16
  float* diag     = (float*)((char*)d_ws + (size_t)2 * NTILE * 8 * 512 * 2);
  float* rowpart  = diag + 2 * NS;                                     // 8 * 16384 f32

  prep_kernel<<<2 * NTILE, 256, 0, stream>>>(users, items, uidx, iidx, Efrag, diag);
  ssm_mfma_kernel<<<2 * 64 * JCHUNKS, 256, 0, stream>>>(Efrag, diag, rowpart);
  finalize_kernel<<<1, 1024, 0, stream>>>(rowpart, out);
}